// Round 3
// baseline (556.016 us; speedup 1.0000x reference)
//
#include <hip/hip_runtime.h>

#define SEQ 128
#define DIM 1024
#define TOPK 51
#define DECAY 0.99f
#define INHIB 1.5f

// ---------------- Kernel A: per-row sparsify (relu + top-k threshold) --------
// One block (256 threads) per row. Exact k-th-largest via 4-pass 8-bit radix
// select on the float bit pattern (monotonic for non-negative floats).
// Bin selection: wave-level __shfl_down suffix-scan (no barriers) + one
// cross-wave LDS combine -> ~3 barriers/pass (was ~19 with Hillis-Steele).
// Also zero-inits the drift^2 accumulator (ws is poisoned 0xAA by harness).
__global__ __launch_bounds__(256) void sparsify_kernel(
    const float* __restrict__ emb, float* __restrict__ s_out,
    int* __restrict__ nnz_idx, int* __restrict__ nnz_cnt,
    float* __restrict__ drift2)
{
    const int t    = blockIdx.x;
    const int tid  = threadIdx.x;
    const int lane = tid & 63;
    const int wave = tid >> 6;
    const float* x = emb + t * DIM;

    float    v[4];
    unsigned u[4];
#pragma unroll
    for (int e = 0; e < 4; ++e) {
        float val = fmaxf(x[e * 256 + tid], 0.0f);   // relu
        v[e] = val;
        u[e] = __float_as_uint(val);
    }

    __shared__ unsigned hist[256];
    __shared__ unsigned wtot[4];
    __shared__ unsigned sh_prefix;
    __shared__ unsigned sh_k;
    __shared__ int      sh_cnt;
    if (tid == 0) { sh_prefix = 0u; sh_k = TOPK; sh_cnt = 0; drift2[t] = 0.0f; }
    hist[tid] = 0u;
    __syncthreads();

    for (int pass = 0; pass < 4; ++pass) {
        const int shift = 24 - 8 * pass;
        const unsigned prefix = sh_prefix;
        const unsigned k      = sh_k;
#pragma unroll
        for (int e = 0; e < 4; ++e) {
            bool ok;
            if (pass == 0) ok = true;
            else           ok = ((u[e] >> (shift + 8)) == (prefix >> (shift + 8)));
            if (ok) atomicAdd(&hist[(u[e] >> shift) & 255u], 1u);
        }
        __syncthreads();

        // Wave-local inclusive suffix-sum over 64 bins (lane i: sum bins i..63)
        unsigned val = hist[tid];
#pragma unroll
        for (int off = 1; off < 64; off <<= 1) {
            unsigned tmp = __shfl_down(val, off, 64);
            if (lane + off < 64) val += tmp;
        }
        if (lane == 0) wtot[wave] = val;   // wave total = suffix from its bin 0
        __syncthreads();

        unsigned addHigher = 0u;
        for (int w = wave + 1; w < 4; ++w) addHigher += wtot[w];
        const unsigned scanFull = val + addHigher;          // suffix over all 256
        const unsigned nxtWithin = __shfl_down(scanFull, 1, 64);
        const unsigned nxt = (lane == 63) ? addHigher : nxtWithin;
        // scanFull non-increasing, scanFull[0]>=k, virtual scanFull[256]=0:
        // exactly one crossing -> bin holding the k-th largest.
        if (scanFull >= k && nxt < k) {
            sh_prefix = prefix | ((unsigned)tid << shift);
            sh_k      = k - nxt;
        }
        hist[tid] = 0u;   // re-zero for next pass (no one reads hist anymore)
        __syncthreads();  // publishes sh_prefix/sh_k AND hist zeroing
    }

    const float thr = __uint_as_float(sh_prefix);
#pragma unroll
    for (int e = 0; e < 4; ++e) {
        const int idx = e * 256 + tid;
        const float sval = (v[e] >= thr) ? v[e] : 0.0f;
        s_out[t * DIM + idx] = sval;
        if (sval > 0.0f) {
            int pos = atomicAdd(&sh_cnt, 1);
            nnz_idx[t * DIM + pos] = idx;
        }
    }
    __syncthreads();
    if (tid == 0) nnz_cnt[t] = sh_cnt;
}

// ---------------- Kernel B: element-parallel state evolution -----------------
// state_t[i,j] = relu(DECAY*state_{t-1}[i,j] + f_t * s_t[i] * s_t[j])
// One i-row per block, thread owns 4 j -> grid 1024, 4 blocks/CU, 16 waves/CU
// of outstanding float4 stores (write-BW bound: 512 MiB mandatory snapshots).
__global__ __launch_bounds__(256) void evolve_kernel(
    const float* __restrict__ s, const float* __restrict__ con,
    float* __restrict__ states)
{
    const int i  = blockIdx.x;
    const int j0 = threadIdx.x * 4;

    float st[4] = {0.f, 0.f, 0.f, 0.f};

    for (int t = 0; t < SEQ; ++t) {
        const float f  = 1.0f - INHIB * con[t];
        const float4 sj = *(const float4*)(s + t * DIM + j0);
        const float si = s[t * DIM + i] * f;

        float4 o;
        o.x = fmaxf(0.0f, DECAY * st[0] + si * sj.x);
        o.y = fmaxf(0.0f, DECAY * st[1] + si * sj.y);
        o.z = fmaxf(0.0f, DECAY * st[2] + si * sj.z);
        o.w = fmaxf(0.0f, DECAY * st[3] + si * sj.w);
        st[0] = o.x; st[1] = o.y; st[2] = o.z; st[3] = o.w;
        *(float4*)(states + (size_t)t * DIM * DIM + (size_t)i * DIM + j0) = o;
    }
}

// ---------------- Kernel C: sparse drift (j-split, partial sum of squares) ---
// drift_t^2 = sum_j (s_j - e_j)^2, e = s_t @ state_{t-1} (only ~TOPK rows).
// Block = (t, j-quarter): 512 blocks, 4x shorter per-block load chains than
// one-block-per-t. Partials atomicAdd into drift2[t]; finisher does sqrt.
__global__ __launch_bounds__(256) void drift_kernel(
    const float* __restrict__ s, const int* __restrict__ nnz_idx,
    const int* __restrict__ nnz_cnt, const float* __restrict__ states,
    float* __restrict__ drift2)
{
    const int t   = blockIdx.x >> 2;
    const int q   = blockIdx.x & 3;
    const int tid = threadIdx.x;
    const int j   = q * 256 + tid;

    __shared__ int   sh_ix[DIM];
    __shared__ float sh_sv[DIM];

    float e = 0.0f;
    if (t > 0) {                        // t is block-uniform: no divergent sync
        const int cnt = nnz_cnt[t];
        for (int n = tid; n < cnt; n += 256) {
            const int i = nnz_idx[t * DIM + n];
            sh_ix[n] = i;
            sh_sv[n] = s[t * DIM + i];
        }
        __syncthreads();

        const float* prev = states + (size_t)(t - 1) * DIM * DIM;
#pragma unroll 4
        for (int n = 0; n < cnt; ++n)
            e += sh_sv[n] * prev[(size_t)sh_ix[n] * DIM + j];
    }
    const float d = s[t * DIM + j] - e;
    float local = d * d;

#pragma unroll
    for (int off = 32; off > 0; off >>= 1)
        local += __shfl_down(local, off, 64);

    __shared__ float wsum[4];
    if ((tid & 63) == 0) wsum[tid >> 6] = local;
    __syncthreads();
    if (tid == 0)
        atomicAdd(&drift2[t], wsum[0] + wsum[1] + wsum[2] + wsum[3]);
}

// ---------------- Kernel D: finisher -----------------------------------------
__global__ void finish_kernel(const float* __restrict__ drift2,
                              float* __restrict__ drift)
{
    const int t = threadIdx.x;
    if (t < SEQ) drift[t] = sqrtf(drift2[t]);
}

extern "C" void kernel_launch(void* const* d_in, const int* in_sizes, int n_in,
                              void* d_out, int out_size, void* d_ws, size_t ws_size,
                              hipStream_t stream)
{
    const float* emb = (const float*)d_in[0];     // [S, D] fp32
    const float* con = (const float*)d_in[1];     // [S]    fp32

    float* drift  = (float*)d_out;                // [S]
    float* states = (float*)d_out + SEQ;          // [S, D, D]

    float* s_buf   = (float*)d_ws;                                    // S*D floats
    int*   nnz_idx = (int*)((char*)d_ws + (size_t)SEQ * DIM * 4);     // S*D ints
    int*   nnz_cnt = (int*)((char*)d_ws + (size_t)2 * SEQ * DIM * 4); // S ints
    float* drift2  = (float*)((char*)d_ws + (size_t)2 * SEQ * DIM * 4 + SEQ * 4);

    sparsify_kernel<<<SEQ, 256, 0, stream>>>(emb, s_buf, nnz_idx, nnz_cnt, drift2);
    evolve_kernel<<<DIM, 256, 0, stream>>>(s_buf, con, states);
    drift_kernel<<<SEQ * 4, 256, 0, stream>>>(s_buf, nnz_idx, nnz_cnt, states, drift2);
    finish_kernel<<<1, 128, 0, stream>>>(drift2, drift);
}

// Round 4
// 543.487 us; speedup vs baseline: 1.0231x; 1.0231x over previous
//
#include <hip/hip_runtime.h>

#define SEQ 128
#define DIM 1024
#define TOPK 51
#define DECAY 0.99f
#define INHIB 1.5f

// ---------------- Kernel A: per-row sparsify (relu + top-k threshold) --------
// One block (256 threads) per row. Exact k-th-largest via 4-pass 8-bit radix
// select on the float bit pattern (monotonic for non-negative floats).
// Bin selection: wave-level __shfl_down suffix-scan (no barriers) + one
// cross-wave LDS combine -> 3 barriers/pass (vs ~19 for Hillis-Steele).
__global__ __launch_bounds__(256) void sparsify_kernel(
    const float* __restrict__ emb, float* __restrict__ s_out,
    int* __restrict__ nnz_idx, int* __restrict__ nnz_cnt)
{
    const int t    = blockIdx.x;
    const int tid  = threadIdx.x;
    const int lane = tid & 63;
    const int wave = tid >> 6;
    const float* x = emb + t * DIM;

    float    v[4];
    unsigned u[4];
#pragma unroll
    for (int e = 0; e < 4; ++e) {
        float val = fmaxf(x[e * 256 + tid], 0.0f);   // relu
        v[e] = val;
        u[e] = __float_as_uint(val);
    }

    __shared__ unsigned hist[256];
    __shared__ unsigned wtot[4];
    __shared__ unsigned sh_prefix;
    __shared__ unsigned sh_k;
    __shared__ int      sh_cnt;
    if (tid == 0) { sh_prefix = 0u; sh_k = TOPK; sh_cnt = 0; }
    hist[tid] = 0u;
    __syncthreads();

    for (int pass = 0; pass < 4; ++pass) {
        const int shift = 24 - 8 * pass;
        const unsigned prefix = sh_prefix;
        const unsigned k      = sh_k;
#pragma unroll
        for (int e = 0; e < 4; ++e) {
            bool ok;
            if (pass == 0) ok = true;
            else           ok = ((u[e] >> (shift + 8)) == (prefix >> (shift + 8)));
            if (ok) atomicAdd(&hist[(u[e] >> shift) & 255u], 1u);
        }
        __syncthreads();

        // Wave-local inclusive suffix-sum over 64 bins (lane i: sum bins i..63)
        unsigned val = hist[tid];
#pragma unroll
        for (int off = 1; off < 64; off <<= 1) {
            unsigned tmp = __shfl_down(val, off, 64);
            if (lane + off < 64) val += tmp;
        }
        if (lane == 0) wtot[wave] = val;   // wave total = suffix from its bin 0
        __syncthreads();

        unsigned addHigher = 0u;
        for (int w = wave + 1; w < 4; ++w) addHigher += wtot[w];
        const unsigned scanFull = val + addHigher;          // suffix over all 256
        const unsigned nxtWithin = __shfl_down(scanFull, 1, 64);
        const unsigned nxt = (lane == 63) ? addHigher : nxtWithin;
        // scanFull non-increasing, scanFull[0]>=k, virtual scanFull[256]=0:
        // exactly one crossing -> bin holding the k-th largest.
        if (scanFull >= k && nxt < k) {
            sh_prefix = prefix | ((unsigned)tid << shift);
            sh_k      = k - nxt;
        }
        hist[tid] = 0u;   // re-zero for next pass (no one reads hist anymore)
        __syncthreads();  // publishes sh_prefix/sh_k AND hist zeroing
    }

    const float thr = __uint_as_float(sh_prefix);
#pragma unroll
    for (int e = 0; e < 4; ++e) {
        const int idx = e * 256 + tid;
        const float sval = (v[e] >= thr) ? v[e] : 0.0f;
        s_out[t * DIM + idx] = sval;
        if (sval > 0.0f) {
            int pos = atomicAdd(&sh_cnt, 1);
            nnz_idx[t * DIM + pos] = idx;
        }
    }
    __syncthreads();
    if (tid == 0) nnz_cnt[t] = sh_cnt;
}

// ---------------- Kernel B: element-parallel state evolution -----------------
// state_t[i,j] = relu(DECAY*state_{t-1}[i,j] + f_t * s_t[i] * s_t[j])
// Each thread owns a 2(i) x 4(j) register tile; block covers full j (1024)
// and 2 i-rows; grid = DIM/2 = 512 blocks -> 2 blocks/CU, 8 waves/CU.
// Write-BW bound: 512 MiB mandatory snapshots @ ~6.2 TB/s ≈ 86 us floor.
// (R3's 1024-block / R2's 512-block variants measured equal within noise;
// keep R2's, the best-measured config.)
__global__ __launch_bounds__(256) void evolve_kernel(
    const float* __restrict__ s, const float* __restrict__ con,
    float* __restrict__ states)
{
    const int i0 = blockIdx.x * 2;
    const int j0 = threadIdx.x * 4;

    float st[2][4];
#pragma unroll
    for (int a = 0; a < 2; ++a)
#pragma unroll
        for (int b = 0; b < 4; ++b) st[a][b] = 0.0f;

    for (int t = 0; t < SEQ; ++t) {
        const float f = 1.0f - INHIB * con[t];
        const float4 sj = *(const float4*)(s + t * DIM + j0);
        float si[2];
#pragma unroll
        for (int a = 0; a < 2; ++a) si[a] = s[t * DIM + i0 + a] * f;

        float* outp = states + (size_t)t * DIM * DIM;
#pragma unroll
        for (int a = 0; a < 2; ++a) {
            float4 o;
            o.x = fmaxf(0.0f, DECAY * st[a][0] + si[a] * sj.x);
            o.y = fmaxf(0.0f, DECAY * st[a][1] + si[a] * sj.y);
            o.z = fmaxf(0.0f, DECAY * st[a][2] + si[a] * sj.z);
            o.w = fmaxf(0.0f, DECAY * st[a][3] + si[a] * sj.w);
            st[a][0] = o.x; st[a][1] = o.y; st[a][2] = o.z; st[a][3] = o.w;
            *(float4*)(outp + (size_t)(i0 + a) * DIM + j0) = o;
        }
    }
}

// ---------------- Kernel C: sparse drift ------------------------------------
// drift_t = || s_t - s_t @ state_{t-1} ||_2 ; only ~TOPK rows of state matter.
// One block (256 threads) per t; thread owns 4 consecutive j (float4 loads,
// 1KB/wave). Index/value list staged in LDS so row loads are independent
// (unroll-4, many in flight). R3's 4-way j-split regressed: it did NOT
// shorten the n-loop (still ~51 iters), only shrank loads to 4B/lane and
// quadrupled staging — keep the R2 form.
__global__ __launch_bounds__(256) void drift_kernel(
    const float* __restrict__ s, const int* __restrict__ nnz_idx,
    const int* __restrict__ nnz_cnt, const float* __restrict__ states,
    float* __restrict__ drift)
{
    const int t   = blockIdx.x;
    const int tid = threadIdx.x;
    const int j0  = tid * 4;

    __shared__ int   sh_ix[DIM];
    __shared__ float sh_sv[DIM];

    float e0 = 0.f, e1 = 0.f, e2 = 0.f, e3 = 0.f;
    if (t > 0) {                       // t is block-uniform: no divergent sync
        const int cnt = nnz_cnt[t];
        for (int n = tid; n < cnt; n += 256) {
            const int i = nnz_idx[t * DIM + n];
            sh_ix[n] = i;
            sh_sv[n] = s[t * DIM + i];
        }
        __syncthreads();

        const float* prev = states + (size_t)(t - 1) * DIM * DIM;
        int n = 0;
        for (; n + 4 <= cnt; n += 4) {
            const int ia = sh_ix[n],     ib = sh_ix[n + 1];
            const int ic = sh_ix[n + 2], id = sh_ix[n + 3];
            const float aa = sh_sv[n],     ab = sh_sv[n + 1];
            const float ac = sh_sv[n + 2], ad = sh_sv[n + 3];
            const float4 ra = *(const float4*)(prev + (size_t)ia * DIM + j0);
            const float4 rb = *(const float4*)(prev + (size_t)ib * DIM + j0);
            const float4 rc = *(const float4*)(prev + (size_t)ic * DIM + j0);
            const float4 rd = *(const float4*)(prev + (size_t)id * DIM + j0);
            e0 += aa * ra.x + ab * rb.x + ac * rc.x + ad * rd.x;
            e1 += aa * ra.y + ab * rb.y + ac * rc.y + ad * rd.y;
            e2 += aa * ra.z + ab * rb.z + ac * rc.z + ad * rd.z;
            e3 += aa * ra.w + ab * rb.w + ac * rc.w + ad * rd.w;
        }
        for (; n < cnt; ++n) {
            const int i = sh_ix[n];
            const float si = sh_sv[n];
            const float4 r = *(const float4*)(prev + (size_t)i * DIM + j0);
            e0 += si * r.x; e1 += si * r.y; e2 += si * r.z; e3 += si * r.w;
        }
    }
    const float4 sj = *(const float4*)(s + t * DIM + j0);
    const float d0 = sj.x - e0, d1 = sj.y - e1, d2 = sj.z - e2, d3 = sj.w - e3;
    float local = d0 * d0 + d1 * d1 + d2 * d2 + d3 * d3;

#pragma unroll
    for (int off = 32; off > 0; off >>= 1)
        local += __shfl_down(local, off, 64);

    __shared__ float wsum[4];
    if ((tid & 63) == 0) wsum[tid >> 6] = local;
    __syncthreads();
    if (tid == 0) drift[t] = sqrtf(wsum[0] + wsum[1] + wsum[2] + wsum[3]);
}

extern "C" void kernel_launch(void* const* d_in, const int* in_sizes, int n_in,
                              void* d_out, int out_size, void* d_ws, size_t ws_size,
                              hipStream_t stream)
{
    const float* emb = (const float*)d_in[0];     // [S, D] fp32
    const float* con = (const float*)d_in[1];     // [S]    fp32

    float* drift  = (float*)d_out;                // [S]
    float* states = (float*)d_out + SEQ;          // [S, D, D]

    float* s_buf   = (float*)d_ws;                                   // S*D floats
    int*   nnz_idx = (int*)((char*)d_ws + (size_t)SEQ * DIM * 4);    // S*D ints
    int*   nnz_cnt = (int*)((char*)d_ws + (size_t)2 * SEQ * DIM * 4);// S ints

    sparsify_kernel<<<SEQ, 256, 0, stream>>>(emb, s_buf, nnz_idx, nnz_cnt);
    evolve_kernel<<<DIM / 2, 256, 0, stream>>>(s_buf, con, states);
    drift_kernel<<<SEQ, 256, 0, stream>>>(s_buf, nnz_idx, nnz_cnt, states, drift);
}